// Round 2
// baseline (167.987 us; speedup 1.0000x reference)
//
#include <hip/hip_runtime.h>

#define NB 8192   // batch
#define NC 1024   // controller width (K)
#define NM 4096   // memory size (N)
#define NCH 64    // NM / 64 (64-col chunks per row)

typedef __attribute__((ext_vector_type(8))) short bf16x8;
typedef __attribute__((ext_vector_type(4))) float f32x4;

__device__ __forceinline__ unsigned short f2bf(float x) {
  unsigned int u = __float_as_uint(x);
  u += 0x7FFFu + ((u >> 16) & 1u);
  return (unsigned short)(u >> 16);
}
__device__ __forceinline__ unsigned int pk2(float a, float b) {
  return (unsigned int)f2bf(a) | ((unsigned int)f2bf(b) << 16);
}

// ---------------- Kernel 1: W [K,N] f32 -> Wt [N,K] bf16 ----------------
__global__ __launch_bounds__(256) void convW_k(const float* __restrict__ W,
                                               unsigned short* __restrict__ Wt) {
  __shared__ float tile[64][65];
  const int n0 = blockIdx.x * 64, k0 = blockIdx.y * 64;
  const int t = threadIdx.x;
  const int r = t >> 2, q = t & 3;
  const float4* src = reinterpret_cast<const float4*>(W + (size_t)(k0 + r) * NM + n0 + q * 16);
  float4 x0 = src[0], x1 = src[1], x2 = src[2], x3 = src[3];
  float* tr = &tile[r][q * 16];
  tr[0]=x0.x; tr[1]=x0.y; tr[2]=x0.z;  tr[3]=x0.w;
  tr[4]=x1.x; tr[5]=x1.y; tr[6]=x1.z;  tr[7]=x1.w;
  tr[8]=x2.x; tr[9]=x2.y; tr[10]=x2.z; tr[11]=x2.w;
  tr[12]=x3.x; tr[13]=x3.y; tr[14]=x3.z; tr[15]=x3.w;
  __syncthreads();
  unsigned int pk[8];
#pragma unroll
  for (int i = 0; i < 8; ++i)
    pk[i] = pk2(tile[q * 16 + 2 * i][r], tile[q * 16 + 2 * i + 1][r]);
  int4* dst = reinterpret_cast<int4*>(Wt + (size_t)(n0 + r) * NC + k0 + q * 16);
  dst[0] = make_int4((int)pk[0], (int)pk[1], (int)pk[2], (int)pk[3]);
  dst[1] = make_int4((int)pk[4], (int)pk[5], (int)pk[6], (int)pk[7]);
}

// ------- Kernel 2: bf16 MFMA GEMM (128x128 tile) + fused row-partials -------
__global__ __launch_bounds__(256) void gemm_fused(
    const float* __restrict__ co, const float* __restrict__ memry,
    const unsigned short* __restrict__ Wt, const float* __restrict__ bvec,
    float* __restrict__ pdotg, float* __restrict__ pesqg,
    float* __restrict__ pmsqg, float* __restrict__ pmsg) {
  __shared__ __align__(16) unsigned short As[128][40];  // pad 32->40: 16B-aligned rows, ~2-way banks
  __shared__ __align__(16) unsigned short Bs[128][40];
  const int bm = blockIdx.x, bn = blockIdx.y;
  const int row0 = bm * 128, col0 = bn * 128;
  const int t = threadIdx.x;
  const int wid = t >> 6, lane = t & 63;
  const int wr = wid >> 1, wc = wid & 1;
  const int l15 = lane & 15, lg = lane >> 4;
  const int srow = t >> 1, shalf = t & 1;

  f32x4 acc[4][4];
#pragma unroll
  for (int mi = 0; mi < 4; ++mi)
#pragma unroll
    for (int ni = 0; ni < 4; ++ni) acc[mi][ni] = (f32x4){0.f, 0.f, 0.f, 0.f};

  const float4* gA = reinterpret_cast<const float4*>(co + (size_t)(row0 + srow) * NC + shalf * 16);

  for (int k0 = 0; k0 < NC; k0 += 32) {
    __syncthreads();
    // stage A (f32 -> bf16 on the fly): 16 f32 per thread
    float4 x0 = gA[(k0 >> 2) + 0], x1 = gA[(k0 >> 2) + 1],
           x2 = gA[(k0 >> 2) + 2], x3 = gA[(k0 >> 2) + 3];
    unsigned int a0 = pk2(x0.x, x0.y), a1 = pk2(x0.z, x0.w),
                 a2 = pk2(x1.x, x1.y), a3 = pk2(x1.z, x1.w),
                 a4 = pk2(x2.x, x2.y), a5 = pk2(x2.z, x2.w),
                 a6 = pk2(x3.x, x3.y), a7 = pk2(x3.z, x3.w);
    *reinterpret_cast<int4*>(&As[srow][shalf * 16]) = make_int4((int)a0, (int)a1, (int)a2, (int)a3);
    *reinterpret_cast<int4*>(&As[srow][shalf * 16 + 8]) = make_int4((int)a4, (int)a5, (int)a6, (int)a7);
    // stage B (already bf16, row-major [N,K] so K is contiguous)
    const int4* gB = reinterpret_cast<const int4*>(Wt + (size_t)(col0 + srow) * NC + k0 + shalf * 16);
    int4 w0 = gB[0], w1 = gB[1];
    *reinterpret_cast<int4*>(&Bs[srow][shalf * 16]) = w0;
    *reinterpret_cast<int4*>(&Bs[srow][shalf * 16 + 8]) = w1;
    __syncthreads();

    bf16x8 af[4], bfv[4];
#pragma unroll
    for (int mi = 0; mi < 4; ++mi)
      af[mi] = *reinterpret_cast<const bf16x8*>(&As[wr * 64 + mi * 16 + l15][lg * 8]);
#pragma unroll
    for (int ni = 0; ni < 4; ++ni)
      bfv[ni] = *reinterpret_cast<const bf16x8*>(&Bs[wc * 64 + ni * 16 + l15][lg * 8]);
#pragma unroll
    for (int mi = 0; mi < 4; ++mi)
#pragma unroll
      for (int ni = 0; ni < 4; ++ni)
        acc[mi][ni] = __builtin_amdgcn_mfma_f32_16x16x32_bf16(af[mi], bfv[ni], acc[mi][ni], 0, 0, 0);
  }

  // epilogue: e = exp(z + b); per-row partials of e*mem, e^2, mem^2, mem
  // partial chunk index: each wave covers a 64-col half => chunk = bn*2 + wc
  float bv[4];
#pragma unroll
  for (int ni = 0; ni < 4; ++ni) bv[ni] = bvec[col0 + wc * 64 + ni * 16 + l15];

  const int chunk = bn * 2 + wc;
#pragma unroll
  for (int mi = 0; mi < 4; ++mi) {
#pragma unroll
    for (int j = 0; j < 4; ++j) {
      const int rowm = row0 + wr * 64 + mi * 16 + 4 * lg + j;
      float pd = 0.f, pe = 0.f, pq = 0.f, pm = 0.f;
#pragma unroll
      for (int ni = 0; ni < 4; ++ni) {
        float e = __expf(acc[mi][ni][j] + bv[ni]);
        float mv = memry[(size_t)rowm * NM + col0 + wc * 64 + ni * 16 + l15];
        pd += e * mv; pe += e * e; pq += mv * mv; pm += mv;
      }
#pragma unroll
      for (int s = 1; s < 16; s <<= 1) {
        pd += __shfl_xor(pd, s);
        pe += __shfl_xor(pe, s);
        pq += __shfl_xor(pq, s);
        pm += __shfl_xor(pm, s);
      }
      if (l15 == 0) {
        const int idx = rowm * NCH + chunk;
        pdotg[idx] = pd; pesqg[idx] = pe; pmsqg[idx] = pq; pmsg[idx] = pm;
      }
    }
  }
}

// ---------------- Kernel 3: reduce partials -> sims, msum ----------------
__global__ __launch_bounds__(256) void finalize_k(
    const float* __restrict__ pd, const float* __restrict__ pe,
    const float* __restrict__ pq, const float* __restrict__ pm,
    float* __restrict__ sims, float* __restrict__ mst) {
  const int r = blockIdx.x * 256 + threadIdx.x;
  float d = 0.f, e = 0.f, q = 0.f, m = 0.f;
#pragma unroll
  for (int i = 0; i < NCH; ++i) {
    d += pd[r * NCH + i];
    e += pe[r * NCH + i];
    q += pq[r * NCH + i];
    m += pm[r * NCH + i];
  }
  sims[r] = -d / (sqrtf(fmaxf(e, 1e-12f)) * sqrtf(fmaxf(q, 1e-12f)));
  mst[r] = m;
}

// ------------- Kernel 4: softmax over B=8192 + final scaling -------------
__global__ __launch_bounds__(1024) void softmax_out_k(
    const float* __restrict__ sims, const float* __restrict__ mst,
    float* __restrict__ out) {
  __shared__ float red[16];
  const int t = threadIdx.x;
  float v[8];
  float mx = -1e30f;
#pragma unroll
  for (int i = 0; i < 8; ++i) {
    v[i] = sims[t + i * 1024];
    mx = fmaxf(mx, v[i]);
  }
#pragma unroll
  for (int s = 1; s < 64; s <<= 1) mx = fmaxf(mx, __shfl_xor(mx, s));
  if ((t & 63) == 0) red[t >> 6] = mx;
  __syncthreads();
  float m2 = red[0];
#pragma unroll
  for (int i = 1; i < 16; ++i) m2 = fmaxf(m2, red[i]);
  mx = m2;
  float sum = 0.f;
#pragma unroll
  for (int i = 0; i < 8; ++i) sum += __expf(v[i] - mx);
#pragma unroll
  for (int s = 1; s < 64; s <<= 1) sum += __shfl_xor(sum, s);
  __syncthreads();
  if ((t & 63) == 0) red[t >> 6] = sum;
  __syncthreads();
  float s2 = 0.f;
#pragma unroll
  for (int i = 0; i < 16; ++i) s2 += red[i];
  const float inv = 1.0f / s2;
#pragma unroll
  for (int i = 0; i < 8; ++i)
    out[t + i * 1024] = __expf(v[i] - mx) * inv * mst[t + i * 1024];
}

extern "C" void kernel_launch(void* const* d_in, const int* in_sizes, int n_in,
                              void* d_out, int out_size, void* d_ws, size_t ws_size,
                              hipStream_t stream) {
  const float* memry = (const float*)d_in[0];  // [B, M]
  const float* co    = (const float*)d_in[1];  // [B, C]
  const float* W     = (const float*)d_in[2];  // [C, M]
  const float* bvec  = (const float*)d_in[3];  // [M]
  float* out = (float*)d_out;                  // [B]

  char* w = (char*)d_ws;
  unsigned short* Wt = (unsigned short*)w;                    // 4096*1024*2 = 8 MiB
  float* pdot = (float*)(w + (size_t)NM * NC * 2);            // 8192*64 f32 each
  float* pesq = pdot + (size_t)NB * NCH;
  float* pmsq = pesq + (size_t)NB * NCH;
  float* pms  = pmsq + (size_t)NB * NCH;
  float* sims = pms  + (size_t)NB * NCH;
  float* mst  = sims + NB;

  convW_k<<<dim3(NM / 64, NC / 64), 256, 0, stream>>>(W, Wt);
  gemm_fused<<<dim3(NB / 128, NM / 128), 256, 0, stream>>>(co, memry, Wt, bvec,
                                                           pdot, pesq, pmsq, pms);
  finalize_k<<<NB / 256, 256, 0, stream>>>(pdot, pesq, pmsq, pms, sims, mst);
  softmax_out_k<<<1, 1024, 0, stream>>>(sims, mst, out);
}

// Round 3
// 136.119 us; speedup vs baseline: 1.2341x; 1.2341x over previous
//
#include <hip/hip_runtime.h>

#define NB 8192   // batch
#define NC 1024   // controller width (K)
#define NM 4096   // memory size (N)
#define NCH 64    // NM / 64 (64-col chunks per row)

typedef __attribute__((ext_vector_type(8))) short bf16x8;
typedef __attribute__((ext_vector_type(4))) float f32x4;

__device__ __forceinline__ unsigned short f2bf(float x) {
  unsigned int u = __float_as_uint(x);
  u += 0x7FFFu + ((u >> 16) & 1u);
  return (unsigned short)(u >> 16);
}
__device__ __forceinline__ unsigned int pk2(float a, float b) {
  return (unsigned int)f2bf(a) | ((unsigned int)f2bf(b) << 16);
}

__device__ __forceinline__ void gload_lds16(const void* g, void* l) {
  __builtin_amdgcn_global_load_lds(
      (const __attribute__((address_space(1))) unsigned int*)g,
      (__attribute__((address_space(3))) unsigned int*)l, 16, 0, 0);
}

// ---------------- Kernel 0: co [B,C] f32 -> bf16 ----------------
__global__ __launch_bounds__(256) void convA_k(const float* __restrict__ src,
                                               unsigned short* __restrict__ dst) {
  const size_t i = ((size_t)blockIdx.x * 256 + threadIdx.x) * 8;
  const float4* s = reinterpret_cast<const float4*>(src + i);
  float4 x0 = s[0], x1 = s[1];
  int4 o = make_int4((int)pk2(x0.x, x0.y), (int)pk2(x0.z, x0.w),
                     (int)pk2(x1.x, x1.y), (int)pk2(x1.z, x1.w));
  *reinterpret_cast<int4*>(dst + i) = o;
}

// ---------------- Kernel 1: W [K,N] f32 -> Wt [N,K] bf16 ----------------
__global__ __launch_bounds__(256) void convW_k(const float* __restrict__ W,
                                               unsigned short* __restrict__ Wt) {
  __shared__ float tile[64][65];
  const int n0 = blockIdx.x * 64, k0 = blockIdx.y * 64;
  const int t = threadIdx.x;
  const int r = t >> 2, q = t & 3;
  const float4* src = reinterpret_cast<const float4*>(W + (size_t)(k0 + r) * NM + n0 + q * 16);
  float4 x0 = src[0], x1 = src[1], x2 = src[2], x3 = src[3];
  float* tr = &tile[r][q * 16];
  tr[0]=x0.x; tr[1]=x0.y; tr[2]=x0.z;  tr[3]=x0.w;
  tr[4]=x1.x; tr[5]=x1.y; tr[6]=x1.z;  tr[7]=x1.w;
  tr[8]=x2.x; tr[9]=x2.y; tr[10]=x2.z; tr[11]=x2.w;
  tr[12]=x3.x; tr[13]=x3.y; tr[14]=x3.z; tr[15]=x3.w;
  __syncthreads();
  unsigned int pk[8];
#pragma unroll
  for (int i = 0; i < 8; ++i)
    pk[i] = pk2(tile[q * 16 + 2 * i][r], tile[q * 16 + 2 * i + 1][r]);
  int4* dst = reinterpret_cast<int4*>(Wt + (size_t)(n0 + r) * NC + k0 + q * 16);
  dst[0] = make_int4((int)pk[0], (int)pk[1], (int)pk[2], (int)pk[3]);
  dst[1] = make_int4((int)pk[4], (int)pk[5], (int)pk[6], (int)pk[7]);
}

// ------- Kernel 2: bf16 MFMA GEMM (128x128 tile, global_load_lds + XOR swizzle)
//         + fused row-partials epilogue -------
__global__ __launch_bounds__(256) void gemm_fused(
    const unsigned short* __restrict__ Abf, const float* __restrict__ memry,
    const unsigned short* __restrict__ Wt, const float* __restrict__ bvec,
    float* __restrict__ pdotg, float* __restrict__ pesqg,
    float* __restrict__ pmsqg, float* __restrict__ pmsg) {
  // linear LDS [128][32] bf16 (8 KiB each); swizzle lives in the addresses
  __shared__ __align__(16) unsigned short As[128 * 32];
  __shared__ __align__(16) unsigned short Bs[128 * 32];
  const int bm = blockIdx.x, bn = blockIdx.y;
  const int row0 = bm * 128, col0 = bn * 128;
  const int t = threadIdx.x;
  const int wid = t >> 6, lane = t & 63;
  const int wr = wid >> 1, wc = wid & 1;
  const int l15 = lane & 15, lg = lane >> 4;

  f32x4 acc[4][4];
#pragma unroll
  for (int mi = 0; mi < 4; ++mi)
#pragma unroll
    for (int ni = 0; ni < 4; ++ni) acc[mi][ni] = (f32x4){0.f, 0.f, 0.f, 0.f};

  // ---- staging address setup (pre-swizzled global source, rule #21) ----
  // inst i, thread t covers LDS bytes t*16 + i*4096  (row = t/4 + i*64, granule = t&3)
  // stored (row, g) must hold k-block (g ^ (row&3)) so reads XOR the same way
  const int srow = t >> 2;
  const int scol = ((t & 3) ^ (srow & 3)) * 8;  // (row+64)&3 == row&3, so same for inst 1
  const unsigned short* gA0 = Abf + (size_t)(row0 + srow) * NC + scol;
  const unsigned short* gA1 = Abf + (size_t)(row0 + srow + 64) * NC + scol;
  const unsigned short* gB0 = Wt + (size_t)(col0 + srow) * NC + scol;
  const unsigned short* gB1 = Wt + (size_t)(col0 + srow + 64) * NC + scol;
  unsigned short* lA0 = As + wid * 512;         // bytes wid*1024
  unsigned short* lA1 = As + 2048 + wid * 512;  // +4096 B
  unsigned short* lB0 = Bs + wid * 512;
  unsigned short* lB1 = Bs + 2048 + wid * 512;

  // ---- fragment read offsets (halfword units), same XOR on read ----
  const int rowa = wr * 64 + l15;  // + mi*16
  const int rowb = wc * 64 + l15;  // + ni*16
  // (rowa + mi*16)&3 == rowa&3
  const int ga = (lg ^ (rowa & 3)) * 8;
  const int gb = (lg ^ (rowb & 3)) * 8;

  for (int k0 = 0; k0 < NC; k0 += 32) {
    __syncthreads();  // previous iter's ds_reads complete before overwrite
    gload_lds16(gA0 + k0, lA0);
    gload_lds16(gA1 + k0, lA1);
    gload_lds16(gB0 + k0, lB0);
    gload_lds16(gB1 + k0, lB1);
    __syncthreads();  // implicit vmcnt(0): staged data visible

    bf16x8 af[4], bfv[4];
#pragma unroll
    for (int mi = 0; mi < 4; ++mi)
      af[mi] = *reinterpret_cast<const bf16x8*>(&As[(rowa + mi * 16) * 32 + ga]);
#pragma unroll
    for (int ni = 0; ni < 4; ++ni)
      bfv[ni] = *reinterpret_cast<const bf16x8*>(&Bs[(rowb + ni * 16) * 32 + gb]);
#pragma unroll
    for (int mi = 0; mi < 4; ++mi)
#pragma unroll
      for (int ni = 0; ni < 4; ++ni)
        acc[mi][ni] = __builtin_amdgcn_mfma_f32_16x16x32_bf16(af[mi], bfv[ni], acc[mi][ni], 0, 0, 0);
  }

  // epilogue: e = exp(z + b); per-row partials of e*mem, e^2, mem^2, mem
  float bv[4];
#pragma unroll
  for (int ni = 0; ni < 4; ++ni) bv[ni] = bvec[col0 + wc * 64 + ni * 16 + l15];

  const int chunk = bn * 2 + wc;
#pragma unroll
  for (int mi = 0; mi < 4; ++mi) {
#pragma unroll
    for (int j = 0; j < 4; ++j) {
      const int rowm = row0 + wr * 64 + mi * 16 + 4 * lg + j;
      float pd = 0.f, pe = 0.f, pq = 0.f, pm = 0.f;
#pragma unroll
      for (int ni = 0; ni < 4; ++ni) {
        float e = __expf(acc[mi][ni][j] + bv[ni]);
        float mv = memry[(size_t)rowm * NM + col0 + wc * 64 + ni * 16 + l15];
        pd += e * mv; pe += e * e; pq += mv * mv; pm += mv;
      }
#pragma unroll
      for (int s = 1; s < 16; s <<= 1) {
        pd += __shfl_xor(pd, s);
        pe += __shfl_xor(pe, s);
        pq += __shfl_xor(pq, s);
        pm += __shfl_xor(pm, s);
      }
      if (l15 == 0) {
        const int idx = rowm * NCH + chunk;
        pdotg[idx] = pd; pesqg[idx] = pe; pmsqg[idx] = pq; pmsg[idx] = pm;
      }
    }
  }
}

// ---------------- Kernel 3: reduce partials -> sims, msum ----------------
__global__ __launch_bounds__(256) void finalize_k(
    const float* __restrict__ pd, const float* __restrict__ pe,
    const float* __restrict__ pq, const float* __restrict__ pm,
    float* __restrict__ sims, float* __restrict__ mst) {
  const int r = blockIdx.x * 256 + threadIdx.x;
  float d = 0.f, e = 0.f, q = 0.f, m = 0.f;
#pragma unroll
  for (int i = 0; i < NCH; ++i) {
    d += pd[r * NCH + i];
    e += pe[r * NCH + i];
    q += pq[r * NCH + i];
    m += pm[r * NCH + i];
  }
  sims[r] = -d / (sqrtf(fmaxf(e, 1e-12f)) * sqrtf(fmaxf(q, 1e-12f)));
  mst[r] = m;
}

// ------------- Kernel 4: softmax over B=8192 + final scaling -------------
__global__ __launch_bounds__(1024) void softmax_out_k(
    const float* __restrict__ sims, const float* __restrict__ mst,
    float* __restrict__ out) {
  __shared__ float red[16];
  const int t = threadIdx.x;
  float v[8];
  float mx = -1e30f;
#pragma unroll
  for (int i = 0; i < 8; ++i) {
    v[i] = sims[t + i * 1024];
    mx = fmaxf(mx, v[i]);
  }
#pragma unroll
  for (int s = 1; s < 64; s <<= 1) mx = fmaxf(mx, __shfl_xor(mx, s));
  if ((t & 63) == 0) red[t >> 6] = mx;
  __syncthreads();
  float m2 = red[0];
#pragma unroll
  for (int i = 1; i < 16; ++i) m2 = fmaxf(m2, red[i]);
  mx = m2;
  float sum = 0.f;
#pragma unroll
  for (int i = 0; i < 8; ++i) sum += __expf(v[i] - mx);
#pragma unroll
  for (int s = 1; s < 64; s <<= 1) sum += __shfl_xor(sum, s);
  __syncthreads();
  if ((t & 63) == 0) red[t >> 6] = sum;
  __syncthreads();
  float s2 = 0.f;
#pragma unroll
  for (int i = 0; i < 16; ++i) s2 += red[i];
  const float inv = 1.0f / s2;
#pragma unroll
  for (int i = 0; i < 8; ++i)
    out[t + i * 1024] = __expf(v[i] - mx) * inv * mst[t + i * 1024];
}

extern "C" void kernel_launch(void* const* d_in, const int* in_sizes, int n_in,
                              void* d_out, int out_size, void* d_ws, size_t ws_size,
                              hipStream_t stream) {
  const float* memry = (const float*)d_in[0];  // [B, M]
  const float* co    = (const float*)d_in[1];  // [B, C]
  const float* W     = (const float*)d_in[2];  // [C, M]
  const float* bvec  = (const float*)d_in[3];  // [M]
  float* out = (float*)d_out;                  // [B]

  char* w = (char*)d_ws;
  unsigned short* Wt  = (unsigned short*)w;                       // 8 MiB
  unsigned short* Abf = Wt + (size_t)NM * NC;                     // 16 MiB
  float* pdot = (float*)(Abf + (size_t)NB * NC);                  // 8192*64 f32 each
  float* pesq = pdot + (size_t)NB * NCH;
  float* pmsq = pesq + (size_t)NB * NCH;
  float* pms  = pmsq + (size_t)NB * NCH;
  float* sims = pms  + (size_t)NB * NCH;
  float* mst  = sims + NB;

  convA_k<<<(size_t)NB * NC / (256 * 8), 256, 0, stream>>>(co, Abf);
  convW_k<<<dim3(NM / 64, NC / 64), 256, 0, stream>>>(W, Wt);
  gemm_fused<<<dim3(NB / 128, NM / 128), 256, 0, stream>>>(Abf, memry, Wt, bvec,
                                                           pdot, pesq, pmsq, pms);
  finalize_k<<<NB / 256, 256, 0, stream>>>(pdot, pesq, pmsq, pms, sims, mst);
  softmax_out_k<<<1, 1024, 0, stream>>>(sims, mst, out);
}